// Round 8
// baseline (596.790 us; speedup 1.0000x reference)
//
#include <hip/hip_runtime.h>
#include <hip/hip_bf16.h>
#include <stdint.h>

#define T_TOKENS 2048
#define HID_DIM 1024
#define INTER 3584
#define NEXP 8
#define PTILES 40   // max padded row-tiles: 4096/128 + 8 alignment pads

typedef float f32x4 __attribute__((ext_vector_type(4)));
typedef short short8 __attribute__((ext_vector_type(8)));
typedef unsigned short ushort8 __attribute__((ext_vector_type(8)));

#define AS1 __attribute__((address_space(1)))
#define AS3 __attribute__((address_space(3)))

__device__ __forceinline__ void gload_lds16(const void* g, void* l) {
    __builtin_amdgcn_global_load_lds((AS1 void*)g, (AS3 void*)l, 16, 0, 0);
}

__device__ __forceinline__ f32x4 mfma16(short8 a, short8 b, f32x4 c) {
    return __builtin_amdgcn_mfma_f32_16x16x32_bf16(a, b, c, 0, 0, 0);
}

__device__ __forceinline__ unsigned short f2bf(float f) {
    union { __hip_bfloat16 h; unsigned short u; } cv;
    cv.h = __float2bfloat16(f);
    return cv.u;
}

__device__ __forceinline__ ushort8 cvt8(float4 v0, float4 v1) {
    ushort8 u;
    u[0] = f2bf(v0.x); u[1] = f2bf(v0.y); u[2] = f2bf(v0.z); u[3] = f2bf(v0.w);
    u[4] = f2bf(v1.x); u[5] = f2bf(v1.y); u[6] = f2bf(v1.z); u[7] = f2bf(v1.w);
    return u;
}

// ---------------- router: fp32 logits, top-2, renorm weights, per-expert counts ----------------
__global__ void router_k(const float* __restrict__ x, const float* __restrict__ gw,
                         int* __restrict__ topk_e, float* __restrict__ topk_w,
                         int* __restrict__ ctl) {
    int lane = threadIdx.x & 63;
    int wid = threadIdx.x >> 6;
    int t = blockIdx.x * 4 + wid;
    const float* xr = x + (size_t)t * HID_DIM;

    float acc[NEXP];
#pragma unroll
    for (int e = 0; e < NEXP; ++e) acc[e] = 0.f;

#pragma unroll
    for (int j = 0; j < 4; ++j) {
        int c = j * 256 + lane * 4;
        float4 v = *reinterpret_cast<const float4*>(xr + c);
#pragma unroll
        for (int e = 0; e < NEXP; ++e) {
            float4 g = *reinterpret_cast<const float4*>(gw + e * HID_DIM + c);
            acc[e] += v.x * g.x + v.y * g.y + v.z * g.z + v.w * g.w;
        }
    }
#pragma unroll
    for (int off = 32; off > 0; off >>= 1)
#pragma unroll
        for (int e = 0; e < NEXP; ++e) acc[e] += __shfl_xor(acc[e], off, 64);

    if (lane == 0) {
        int e0 = 0;
#pragma unroll
        for (int e = 1; e < NEXP; ++e) if (acc[e] > acc[e0]) e0 = e;
        int e1 = -1;
        float b1 = 0.f;
#pragma unroll
        for (int e = 0; e < NEXP; ++e) {
            if (e == e0) continue;
            if (e1 < 0 || acc[e] > b1) { e1 = e; b1 = acc[e]; }
        }
        float p1 = __expf(b1 - acc[e0]);
        float s = 1.f + p1;
        topk_e[2 * t] = e0; topk_e[2 * t + 1] = e1;
        topk_w[2 * t] = 1.f / s; topk_w[2 * t + 1] = p1 / s;
        atomicAdd(&ctl[e0], 1);
        atomicAdd(&ctl[e1], 1);
    }
}

// ctl: [0..8) counts, [16..24) cursors, [32..40) 128-aligned offsets,
//      [48] = n_slots, [64..64+40) slot table (e<<16|tm)
__global__ void prefix_k(int* __restrict__ ctl) {
    if (threadIdx.x == 0) {
        int r = 0, ns = 0;
        for (int e = 0; e < NEXP; ++e) {
            ctl[32 + e] = r;
            int c = ctl[e];
            r += (c + 127) & ~127;
            ctl[16 + e] = 0;
            int ntm = (c + 127) >> 7;
            for (int tm = 0; tm < ntm; ++tm) ctl[64 + ns++] = (e << 16) | tm;
        }
        ctl[48] = ns;
    }
}

__global__ void scatter_k(const int* __restrict__ topk_e, const float* __restrict__ topk_w,
                          int* __restrict__ ctl, int* __restrict__ perm_token,
                          float* __restrict__ perm_gate) {
    int t = blockIdx.x * 256 + threadIdx.x;
    if (t >= T_TOKENS) return;
#pragma unroll
    for (int k = 0; k < 2; ++k) {
        int e = topk_e[2 * t + k];
        int p = ctl[32 + e] + atomicAdd(&ctl[16 + e], 1);
        perm_token[p] = t;
        perm_gate[p] = topk_w[2 * t + k];
    }
}

// ---- gather routed tokens into packed A layout [ptile][kt16][kb8][row128][8], fp32->bf16 ----
__global__ __launch_bounds__(256) void pack_x_k(const float* __restrict__ x,
                                                const int* __restrict__ perm_token,
                                                unsigned short* __restrict__ xgp) {
    int ptile = blockIdx.x;
    int kt = blockIdx.y;
    int row = threadIdx.x & 127;
    int kh = threadIdx.x >> 7;  // 0..1: 32 k each (4 kb)
    int tok = perm_token[ptile * 128 + row];
    const float* s = x + (size_t)tok * HID_DIM + kt * 64 + kh * 32;
    unsigned short* d = xgp + (size_t)ptile * 131072 + (size_t)kt * 8192;
#pragma unroll
    for (int kb2 = 0; kb2 < 4; ++kb2) {
        int kb = kh * 4 + kb2;
        float4 v0 = *reinterpret_cast<const float4*>(s + kb2 * 8);
        float4 v1 = *reinterpret_cast<const float4*>(s + kb2 * 8 + 4);
        *reinterpret_cast<ushort8*>(d + (kb * 128 + row) * 8) = cvt8(v0, v1);
    }
}

// ---------------- GEMM1 (fused cvt): hid = silu(Xg@w1^T)*(Xg@w3^T) ----------------
// 512 thr / 8 waves (2x4). BM=128, BN=128 per matrix, BK=64. LDS 48KB.
// B is reg-staged from fp32 w1/w3 (cvt->ds_write); next-tile loads issued after
// bar1 so HBM/L2 latency overlaps the MFMA phase. A via global_load_lds from xgp.
// Grid (224, 5): nt = x>>3, slot = (x&7)*5 + y -> same-expert slots share an XCD L2.
__global__ __launch_bounds__(512) void gemm1_k(
    const unsigned short* __restrict__ xgp,
    const float* __restrict__ w1, const float* __restrict__ w3,
    const int* __restrict__ ctl, unsigned short* __restrict__ hidp) {
    int ns = ctl[48];
    int nt = blockIdx.x >> 3;                       // 0..27
    int slot = (blockIdx.x & 7) * 5 + blockIdx.y;   // 0..39
    if (slot >= ns) return;
    int et = ctl[64 + slot];
    int e = et >> 16, tm = et & 0xffff;
    int cnt = ctl[e];
    int off = ctl[32 + e];
    int ptile = (off >> 7) + tm;

    __shared__ __attribute__((aligned(16))) unsigned short A_l[8192];   // [kb8][row128][8] 16KB
    __shared__ __attribute__((aligned(16))) unsigned short B1_l[8192];  // [kb8][col128][8] 16KB
    __shared__ __attribute__((aligned(16))) unsigned short B3_l[8192];

    int tid = threadIdx.x;
    int lane = tid & 63;
    int wid = tid >> 6;
    int wr = wid >> 2, wc = wid & 3;   // 2 x 4 waves: 64 rows x 32 cols each
    int q = lane >> 4, rr = lane & 15;

    const unsigned short* asrc = xgp + (size_t)ptile * 131072;

    // B staging mapping: col = tid&127, kh = tid>>7 (16 consecutive k each)
    int col = tid & 127;
    int kh = tid >> 7;   // 0..3
    const float* b1s = w1 + ((size_t)e * INTER + nt * 128 + col) * HID_DIM + kh * 16;
    const float* b3s = w3 + ((size_t)e * INTER + nt * 128 + col) * HID_DIM + kh * 16;
    int bo0 = ((kh * 2 + 0) * 128 + col) * 8;  // shorts
    int bo1 = ((kh * 2 + 1) * 128 + col) * 8;

    f32x4 acc1[4][2], acc3[4][2];
#pragma unroll
    for (int i = 0; i < 4; ++i)
#pragma unroll
        for (int j = 0; j < 2; ++j) { acc1[i][j] = 0.f; acc3[i][j] = 0.f; }

    float4 r10, r11, r12, r13, r30, r31, r32, r33;
#define G1_LOADB(KT) do {                                                     \
        const float* p1_ = b1s + (size_t)(KT) * 64;                           \
        const float* p3_ = b3s + (size_t)(KT) * 64;                           \
        r10 = *reinterpret_cast<const float4*>(p1_);                          \
        r11 = *reinterpret_cast<const float4*>(p1_ + 4);                      \
        r12 = *reinterpret_cast<const float4*>(p1_ + 8);                      \
        r13 = *reinterpret_cast<const float4*>(p1_ + 12);                     \
        r30 = *reinterpret_cast<const float4*>(p3_);                          \
        r31 = *reinterpret_cast<const float4*>(p3_ + 4);                      \
        r32 = *reinterpret_cast<const float4*>(p3_ + 8);                      \
        r33 = *reinterpret_cast<const float4*>(p3_ + 12);                     \
    } while (0)

    G1_LOADB(0);
    for (int kt = 0; kt < 16; ++kt) {
        const unsigned short* as_ = asrc + (size_t)kt * 8192;
        gload_lds16(as_ + tid * 8, A_l + tid * 8);
        gload_lds16(as_ + (512 + tid) * 8, A_l + (512 + tid) * 8);
        *reinterpret_cast<ushort8*>(B1_l + bo0) = cvt8(r10, r11);
        *reinterpret_cast<ushort8*>(B1_l + bo1) = cvt8(r12, r13);
        *reinterpret_cast<ushort8*>(B3_l + bo0) = cvt8(r30, r31);
        *reinterpret_cast<ushort8*>(B3_l + bo1) = cvt8(r32, r33);
        __syncthreads();                       // A landed + ds_writes visible
        if (kt < 15) G1_LOADB(kt + 1);         // overlap HBM/L2 latency with MFMA
#pragma unroll
        for (int kk = 0; kk < 2; ++kk) {
            short8 a[4], b1v[2], b3v[2];
            const unsigned short* abase = A_l + ((kk * 4 + q) * 128 + wr * 64 + rr) * 8;
#pragma unroll
            for (int i = 0; i < 4; ++i) a[i] = *reinterpret_cast<const short8*>(abase + i * 128);
            const unsigned short* b1base = B1_l + ((kk * 4 + q) * 128 + wc * 32 + rr) * 8;
            const unsigned short* b3base = B3_l + ((kk * 4 + q) * 128 + wc * 32 + rr) * 8;
#pragma unroll
            for (int j = 0; j < 2; ++j) {
                b1v[j] = *reinterpret_cast<const short8*>(b1base + j * 128);
                b3v[j] = *reinterpret_cast<const short8*>(b3base + j * 128);
            }
#pragma unroll
            for (int i = 0; i < 4; ++i)
#pragma unroll
                for (int j = 0; j < 2; ++j) {
                    acc1[i][j] = mfma16(a[i], b1v[j], acc1[i][j]);
                    acc3[i][j] = mfma16(a[i], b3v[j], acc3[i][j]);
                }
        }
        __syncthreads();   // readers done before next overwrite; drains next-B regs (needed anyway)
    }
#undef G1_LOADB

    // epilogue: silu(g)*u -> packed hid [ptile][tile64][kb][row][8]
    int rbase = wr * 64 + q * 4;
#pragma unroll
    for (int i = 0; i < 4; ++i) {
#pragma unroll
        for (int r = 0; r < 4; ++r) {
            int lrow = rbase + i * 16 + r;
            if (tm * 128 + lrow < cnt) {
#pragma unroll
                for (int j = 0; j < 2; ++j) {
                    int cw = wc * 32 + j * 16 + rr;     // 0..127 within this 128-col tile
                    int tile = nt * 2 + (cw >> 6);
                    int cl = cw & 63;
                    float g = acc1[i][j][r];
                    float u = acc3[i][j][r];
                    float h = (g / (1.f + __expf(-g))) * u;
                    hidp[(size_t)(ptile * 56 + tile) * 8192 + ((cl >> 3) * 128 + lrow) * 8 + (cl & 7)] = f2bf(h);
                }
            }
        }
    }
}

// ---------------- GEMM2 (fused cvt): out[tok] += gate*(hid @ w2^T) ----------------
// 512 thr / 8 waves (2x4). BM=128, BN=256, BK=64, 2-way K-split. LDS 48KB.
// Grid (32, 5, 2): nt = x>>3 (256-col tiles), slot = (x&7)*5 + y, ks = z.
__global__ __launch_bounds__(512) void gemm2_k(
    const unsigned short* __restrict__ hidp, const float* __restrict__ w2,
    const int* __restrict__ ctl, const int* __restrict__ perm_token,
    const float* __restrict__ perm_gate, float* __restrict__ out) {
    int ns = ctl[48];
    int nt = blockIdx.x >> 3;                       // 0..3
    int slot = (blockIdx.x & 7) * 5 + blockIdx.y;   // 0..39
    if (slot >= ns) return;
    int et = ctl[64 + slot];
    int e = et >> 16, tm = et & 0xffff;
    int ks = blockIdx.z;              // kt in [ks*28, ks*28+28)
    int cnt = ctl[e];
    int off = ctl[32 + e];
    int ptile = (off >> 7) + tm;

    __shared__ __attribute__((aligned(16))) unsigned short A_l[8192];   // [kb8][row128][8] 16KB
    __shared__ __attribute__((aligned(16))) unsigned short B_l[16384];  // [kb8][col256][8] 32KB

    int tid = threadIdx.x;
    int lane = tid & 63;
    int wid = tid >> 6;
    int wr = wid >> 2, wc = wid & 3;   // 2 x 4 waves: 64 rows x 64 cols each
    int q = lane >> 4, rr = lane & 15;

    const unsigned short* asrc = hidp + (size_t)(ptile * 56) * 8192;

    int col = tid & 255;
    int kh = tid >> 8;   // 0..1, 32 consecutive k each
    const float* bs = w2 + ((size_t)e * HID_DIM + nt * 256 + col) * INTER + kh * 32;
    int bo0 = ((kh * 4 + 0) * 256 + col) * 8;
    int bo1 = ((kh * 4 + 1) * 256 + col) * 8;
    int bo2 = ((kh * 4 + 2) * 256 + col) * 8;
    int bo3 = ((kh * 4 + 3) * 256 + col) * 8;

    f32x4 acc[4][4];
#pragma unroll
    for (int i = 0; i < 4; ++i)
#pragma unroll
        for (int j = 0; j < 4; ++j) acc[i][j] = 0.f;

    float4 s0, s1, s2, s3, s4, s5, s6, s7;
#define G2_LOADB(KT) do {                                                     \
        const float* p_ = bs + (size_t)(KT) * 64;                             \
        s0 = *reinterpret_cast<const float4*>(p_);                            \
        s1 = *reinterpret_cast<const float4*>(p_ + 4);                        \
        s2 = *reinterpret_cast<const float4*>(p_ + 8);                        \
        s3 = *reinterpret_cast<const float4*>(p_ + 12);                       \
        s4 = *reinterpret_cast<const float4*>(p_ + 16);                       \
        s5 = *reinterpret_cast<const float4*>(p_ + 20);                       \
        s6 = *reinterpret_cast<const float4*>(p_ + 24);                       \
        s7 = *reinterpret_cast<const float4*>(p_ + 28);                       \
    } while (0)

    int kt0 = ks * 28;
    G2_LOADB(kt0);
    for (int t = 0; t < 28; ++t) {
        int kt = kt0 + t;
        const unsigned short* as_ = asrc + (size_t)kt * 8192;
        gload_lds16(as_ + tid * 8, A_l + tid * 8);
        gload_lds16(as_ + (512 + tid) * 8, A_l + (512 + tid) * 8);
        *reinterpret_cast<ushort8*>(B_l + bo0) = cvt8(s0, s1);
        *reinterpret_cast<ushort8*>(B_l + bo1) = cvt8(s2, s3);
        *reinterpret_cast<ushort8*>(B_l + bo2) = cvt8(s4, s5);
        *reinterpret_cast<ushort8*>(B_l + bo3) = cvt8(s6, s7);
        __syncthreads();
        if (t < 27) G2_LOADB(kt + 1);          // overlap with MFMA phase
#pragma unroll
        for (int kk = 0; kk < 2; ++kk) {
            short8 a[4], b[4];
            const unsigned short* abase = A_l + ((kk * 4 + q) * 128 + wr * 64 + rr) * 8;
            const unsigned short* bbase = B_l + ((kk * 4 + q) * 256 + wc * 64 + rr) * 8;
#pragma unroll
            for (int i = 0; i < 4; ++i) a[i] = *reinterpret_cast<const short8*>(abase + i * 128);
#pragma unroll
            for (int j = 0; j < 4; ++j) b[j] = *reinterpret_cast<const short8*>(bbase + j * 128);
#pragma unroll
            for (int i = 0; i < 4; ++i)
#pragma unroll
                for (int j = 0; j < 4; ++j) acc[i][j] = mfma16(a[i], b[j], acc[i][j]);
        }
        __syncthreads();
    }
#undef G2_LOADB

    int rb = wr * 64 + q * 4;
    int hb = nt * 256 + wc * 64 + rr;
#pragma unroll
    for (int i = 0; i < 4; ++i) {
#pragma unroll
        for (int r = 0; r < 4; ++r) {
            int lrow = rb + i * 16 + r;
            int grow = tm * 128 + lrow;
            if (grow < cnt) {
                int p = off + grow;
                int tok = perm_token[p];
                float gate = perm_gate[p];
#pragma unroll
                for (int j = 0; j < 4; ++j)
                    atomicAdd(&out[(size_t)tok * HID_DIM + hb + j * 16], acc[i][j][r] * gate);
            }
        }
    }
}

extern "C" void kernel_launch(void* const* d_in, const int* in_sizes, int n_in,
                              void* d_out, int out_size, void* d_ws, size_t ws_size,
                              hipStream_t stream) {
    const float* x  = (const float*)d_in[0];
    const float* gw = (const float*)d_in[1];
    const float* w1 = (const float*)d_in[2];
    const float* w2 = (const float*)d_in[3];
    const float* w3 = (const float*)d_in[4];
    float* out = (float*)d_out;

    char* ws = (char*)d_ws;
    int*   ctl        = (int*)ws;                              // 4KB
    int*   topk_e     = (int*)(ws + 4096);                     // 16KB
    float* topk_w     = (float*)(ws + 20480);                  // 16KB
    int*   perm_token = (int*)(ws + 36864);                    // 20KB (5120)
    float* perm_gate  = (float*)(ws + 57344);                  // 20KB
    unsigned short* xgp  = (unsigned short*)(ws + (1ull << 20));        // 10.49MB @1MB
    unsigned short* hidp = (unsigned short*)(ws + 12582912);            // 36.7MB @12MB

    hipMemsetAsync(ctl, 0, 512, stream);
    hipMemsetAsync(perm_token, 0, PTILES * 128 * sizeof(int), stream);
    hipMemsetAsync(out, 0, (size_t)out_size * sizeof(float), stream);

    router_k<<<dim3(T_TOKENS / 4), 256, 0, stream>>>(x, gw, topk_e, topk_w, ctl);
    prefix_k<<<dim3(1), 64, 0, stream>>>(ctl);
    scatter_k<<<dim3(T_TOKENS / 256), 256, 0, stream>>>(topk_e, topk_w, ctl, perm_token, perm_gate);
    pack_x_k<<<dim3(PTILES, 16), 256, 0, stream>>>(x, perm_token, xgp);
    gemm1_k<<<dim3(224, 5), 512, 0, stream>>>(xgp, w1, w3, ctl, hidp);
    gemm2_k<<<dim3(32, 5, 2), 512, 0, stream>>>(hidp, w2, ctl, perm_token, perm_gate, out);
}

// Round 9
// 504.347 us; speedup vs baseline: 1.1833x; 1.1833x over previous
//
#include <hip/hip_runtime.h>
#include <hip/hip_bf16.h>
#include <stdint.h>

#define T_TOKENS 2048
#define HID_DIM 1024
#define INTER 3584
#define NEXP 8
#define PTILES 40   // max padded row-tiles: 4096/128 + 8 alignment pads

typedef float f32x4 __attribute__((ext_vector_type(4)));
typedef short short8 __attribute__((ext_vector_type(8)));
typedef unsigned short ushort8 __attribute__((ext_vector_type(8)));

#define AS1 __attribute__((address_space(1)))
#define AS3 __attribute__((address_space(3)))

#define BPAD1 129   // gemm1 B LDS col-dim pad (write-bank spread)
#define BPAD2 257   // gemm2 B LDS col-dim pad

__device__ __forceinline__ void gload_lds16(const void* g, void* l) {
    __builtin_amdgcn_global_load_lds((AS1 void*)g, (AS3 void*)l, 16, 0, 0);
}

__device__ __forceinline__ f32x4 mfma16(short8 a, short8 b, f32x4 c) {
    return __builtin_amdgcn_mfma_f32_16x16x32_bf16(a, b, c, 0, 0, 0);
}

__device__ __forceinline__ unsigned short f2bf(float f) {
    union { __hip_bfloat16 h; unsigned short u; } cv;
    cv.h = __float2bfloat16(f);
    return cv.u;
}

__device__ __forceinline__ ushort8 cvt8(float4 v0, float4 v1) {
    ushort8 u;
    u[0] = f2bf(v0.x); u[1] = f2bf(v0.y); u[2] = f2bf(v0.z); u[3] = f2bf(v0.w);
    u[4] = f2bf(v1.x); u[5] = f2bf(v1.y); u[6] = f2bf(v1.z); u[7] = f2bf(v1.w);
    return u;
}

// ---------------- router: fp32 logits, top-2, renorm weights, per-expert counts ----------------
__global__ void router_k(const float* __restrict__ x, const float* __restrict__ gw,
                         int* __restrict__ topk_e, float* __restrict__ topk_w,
                         int* __restrict__ ctl) {
    int lane = threadIdx.x & 63;
    int wid = threadIdx.x >> 6;
    int t = blockIdx.x * 4 + wid;
    const float* xr = x + (size_t)t * HID_DIM;

    float acc[NEXP];
#pragma unroll
    for (int e = 0; e < NEXP; ++e) acc[e] = 0.f;

#pragma unroll
    for (int j = 0; j < 4; ++j) {
        int c = j * 256 + lane * 4;
        float4 v = *reinterpret_cast<const float4*>(xr + c);
#pragma unroll
        for (int e = 0; e < NEXP; ++e) {
            float4 g = *reinterpret_cast<const float4*>(gw + e * HID_DIM + c);
            acc[e] += v.x * g.x + v.y * g.y + v.z * g.z + v.w * g.w;
        }
    }
#pragma unroll
    for (int off = 32; off > 0; off >>= 1)
#pragma unroll
        for (int e = 0; e < NEXP; ++e) acc[e] += __shfl_xor(acc[e], off, 64);

    if (lane == 0) {
        int e0 = 0;
#pragma unroll
        for (int e = 1; e < NEXP; ++e) if (acc[e] > acc[e0]) e0 = e;
        int e1 = -1;
        float b1 = 0.f;
#pragma unroll
        for (int e = 0; e < NEXP; ++e) {
            if (e == e0) continue;
            if (e1 < 0 || acc[e] > b1) { e1 = e; b1 = acc[e]; }
        }
        float p1 = __expf(b1 - acc[e0]);
        float s = 1.f + p1;
        topk_e[2 * t] = e0; topk_e[2 * t + 1] = e1;
        topk_w[2 * t] = 1.f / s; topk_w[2 * t + 1] = p1 / s;
        atomicAdd(&ctl[e0], 1);
        atomicAdd(&ctl[e1], 1);
    }
}

// ctl: [0..8) counts, [16..24) cursors, [32..40) 128-aligned offsets,
//      [48] = n_slots, [64..64+40) slot table (e<<16|tm)
__global__ void prefix_k(int* __restrict__ ctl) {
    if (threadIdx.x == 0) {
        int r = 0, ns = 0;
        for (int e = 0; e < NEXP; ++e) {
            ctl[32 + e] = r;
            int c = ctl[e];
            r += (c + 127) & ~127;
            ctl[16 + e] = 0;
            int ntm = (c + 127) >> 7;
            for (int tm = 0; tm < ntm; ++tm) ctl[64 + ns++] = (e << 16) | tm;
        }
        ctl[48] = ns;
    }
}

__global__ void scatter_k(const int* __restrict__ topk_e, const float* __restrict__ topk_w,
                          int* __restrict__ ctl, int* __restrict__ perm_token,
                          float* __restrict__ perm_gate) {
    int t = blockIdx.x * 256 + threadIdx.x;
    if (t >= T_TOKENS) return;
#pragma unroll
    for (int k = 0; k < 2; ++k) {
        int e = topk_e[2 * t + k];
        int p = ctl[32 + e] + atomicAdd(&ctl[16 + e], 1);
        perm_token[p] = t;
        perm_gate[p] = topk_w[2 * t + k];
    }
}

// ---- gather routed tokens into packed A layout [ptile][kt16][kb8][row128][8], fp32->bf16 ----
__global__ __launch_bounds__(256) void pack_x_k(const float* __restrict__ x,
                                                const int* __restrict__ perm_token,
                                                unsigned short* __restrict__ xgp) {
    int ptile = blockIdx.x;
    int kt = blockIdx.y;
    int row = threadIdx.x & 127;
    int kh = threadIdx.x >> 7;  // 0..1: 32 k each (4 kb)
    int tok = perm_token[ptile * 128 + row];
    const float* s = x + (size_t)tok * HID_DIM + kt * 64 + kh * 32;
    unsigned short* d = xgp + (size_t)ptile * 131072 + (size_t)kt * 8192;
#pragma unroll
    for (int kb2 = 0; kb2 < 4; ++kb2) {
        int kb = kh * 4 + kb2;
        float4 v0 = *reinterpret_cast<const float4*>(s + kb2 * 8);
        float4 v1 = *reinterpret_cast<const float4*>(s + kb2 * 8 + 4);
        *reinterpret_cast<ushort8*>(d + (kb * 128 + row) * 8) = cvt8(v0, v1);
    }
}

// ---------------- GEMM1 (fused cvt, coalesced): hid = silu(Xg@w1^T)*(Xg@w3^T) ----------------
// 512 thr / 8 waves (2x4). BM=128, BN=128 per matrix, BK=64. LDS ~48KB, 3 blocks/CU.
// B reg-staged from fp32: thread t -> row t>>2, k-quarter t&3 (16 consecutive floats),
// so every load instruction covers full 64B lines. LDS B col-dim padded to 129.
// Grid (224, 5): nt = x>>3, slot = (x&7)*5 + y -> same (e,nt) readers temporally close (L3).
__global__ __launch_bounds__(512) void gemm1_k(
    const unsigned short* __restrict__ xgp,
    const float* __restrict__ w1, const float* __restrict__ w3,
    const int* __restrict__ ctl, unsigned short* __restrict__ hidp) {
    int ns = ctl[48];
    int nt = blockIdx.x >> 3;                       // 0..27
    int slot = (blockIdx.x & 7) * 5 + blockIdx.y;   // 0..39
    if (slot >= ns) return;
    int et = ctl[64 + slot];
    int e = et >> 16, tm = et & 0xffff;
    int cnt = ctl[e];
    int off = ctl[32 + e];
    int ptile = (off >> 7) + tm;

    __shared__ __attribute__((aligned(16))) unsigned short A_l[8192];            // [kb8][row128][8] 16KB
    __shared__ __attribute__((aligned(16))) unsigned short B1_l[8 * BPAD1 * 8];  // [kb8][col129][8]
    __shared__ __attribute__((aligned(16))) unsigned short B3_l[8 * BPAD1 * 8];

    int tid = threadIdx.x;
    int lane = tid & 63;
    int wid = tid >> 6;
    int wr = wid >> 2, wc = wid & 3;   // 2 x 4 waves: 64 rows x 32 cols each
    int q = lane >> 4, rr = lane & 15;

    const unsigned short* asrc = xgp + (size_t)ptile * 131072;

    // B staging: c = tid>>2 (row of w), kq = tid&3 (16 consecutive k)
    int c = tid >> 2;
    int kq = tid & 3;
    const float* b1s = w1 + ((size_t)e * INTER + nt * 128 + c) * HID_DIM + kq * 16;
    const float* b3s = w3 + ((size_t)e * INTER + nt * 128 + c) * HID_DIM + kq * 16;
    int bo0 = ((kq * 2 + 0) * BPAD1 + c) * 8;   // shorts
    int bo1 = ((kq * 2 + 1) * BPAD1 + c) * 8;

    f32x4 acc1[4][2], acc3[4][2];
#pragma unroll
    for (int i = 0; i < 4; ++i)
#pragma unroll
        for (int j = 0; j < 2; ++j) { acc1[i][j] = 0.f; acc3[i][j] = 0.f; }

    float4 r10, r11, r12, r13, r30, r31, r32, r33;
#define G1_LOADB(KT) do {                                                     \
        const float* p1_ = b1s + (size_t)(KT) * 64;                           \
        const float* p3_ = b3s + (size_t)(KT) * 64;                           \
        r10 = *reinterpret_cast<const float4*>(p1_);                          \
        r11 = *reinterpret_cast<const float4*>(p1_ + 4);                      \
        r12 = *reinterpret_cast<const float4*>(p1_ + 8);                      \
        r13 = *reinterpret_cast<const float4*>(p1_ + 12);                     \
        r30 = *reinterpret_cast<const float4*>(p3_);                          \
        r31 = *reinterpret_cast<const float4*>(p3_ + 4);                      \
        r32 = *reinterpret_cast<const float4*>(p3_ + 8);                      \
        r33 = *reinterpret_cast<const float4*>(p3_ + 12);                     \
    } while (0)

    G1_LOADB(0);
    for (int kt = 0; kt < 16; ++kt) {
        const unsigned short* as_ = asrc + (size_t)kt * 8192;
        gload_lds16(as_ + tid * 8, A_l + tid * 8);
        gload_lds16(as_ + (512 + tid) * 8, A_l + (512 + tid) * 8);
        *reinterpret_cast<ushort8*>(B1_l + bo0) = cvt8(r10, r11);
        *reinterpret_cast<ushort8*>(B1_l + bo1) = cvt8(r12, r13);
        *reinterpret_cast<ushort8*>(B3_l + bo0) = cvt8(r30, r31);
        *reinterpret_cast<ushort8*>(B3_l + bo1) = cvt8(r32, r33);
        __syncthreads();                       // A landed + ds_writes visible
        if (kt < 15) G1_LOADB(kt + 1);         // prefetch overlaps MFMA phase
#pragma unroll
        for (int kk = 0; kk < 2; ++kk) {
            short8 a[4], b1v[2], b3v[2];
            const unsigned short* abase = A_l + ((kk * 4 + q) * 128 + wr * 64 + rr) * 8;
#pragma unroll
            for (int i = 0; i < 4; ++i) a[i] = *reinterpret_cast<const short8*>(abase + i * 128);
            const unsigned short* b1base = B1_l + ((kk * 4 + q) * BPAD1 + wc * 32 + rr) * 8;
            const unsigned short* b3base = B3_l + ((kk * 4 + q) * BPAD1 + wc * 32 + rr) * 8;
#pragma unroll
            for (int j = 0; j < 2; ++j) {
                b1v[j] = *reinterpret_cast<const short8*>(b1base + j * 128);
                b3v[j] = *reinterpret_cast<const short8*>(b3base + j * 128);
            }
#pragma unroll
            for (int i = 0; i < 4; ++i)
#pragma unroll
                for (int j = 0; j < 2; ++j) {
                    acc1[i][j] = mfma16(a[i], b1v[j], acc1[i][j]);
                    acc3[i][j] = mfma16(a[i], b3v[j], acc3[i][j]);
                }
        }
        __syncthreads();
    }
#undef G1_LOADB

    // epilogue: silu(g)*u -> packed hid [ptile][tile64][kb][row][8]
    int rbase = wr * 64 + q * 4;
#pragma unroll
    for (int i = 0; i < 4; ++i) {
#pragma unroll
        for (int r = 0; r < 4; ++r) {
            int lrow = rbase + i * 16 + r;
            if (tm * 128 + lrow < cnt) {
#pragma unroll
                for (int j = 0; j < 2; ++j) {
                    int cw = wc * 32 + j * 16 + rr;     // 0..127 within this 128-col tile
                    int tile = nt * 2 + (cw >> 6);
                    int cl = cw & 63;
                    float g = acc1[i][j][r];
                    float u = acc3[i][j][r];
                    float h = (g / (1.f + __expf(-g))) * u;
                    hidp[(size_t)(ptile * 56 + tile) * 8192 + ((cl >> 3) * 128 + lrow) * 8 + (cl & 7)] = f2bf(h);
                }
            }
        }
    }
}

// ---------------- GEMM2 (fused cvt, coalesced): out[tok] += gate*(hid @ w2^T) ----------------
// 512 thr / 8 waves (2x4). BM=128, BN=256, BK=64, 4-way K-split. LDS ~48KB.
// Grid (32, 5, 4): nt = x>>3 (256-col tiles), slot = (x&7)*5 + y, ks = z (14 kt each).
__global__ __launch_bounds__(512) void gemm2_k(
    const unsigned short* __restrict__ hidp, const float* __restrict__ w2,
    const int* __restrict__ ctl, const int* __restrict__ perm_token,
    const float* __restrict__ perm_gate, float* __restrict__ out) {
    int ns = ctl[48];
    int nt = blockIdx.x >> 3;                       // 0..3
    int slot = (blockIdx.x & 7) * 5 + blockIdx.y;   // 0..39
    if (slot >= ns) return;
    int et = ctl[64 + slot];
    int e = et >> 16, tm = et & 0xffff;
    int ks = blockIdx.z;              // kt in [ks*14, ks*14+14)
    int cnt = ctl[e];
    int off = ctl[32 + e];
    int ptile = (off >> 7) + tm;

    __shared__ __attribute__((aligned(16))) unsigned short A_l[8192];            // [kb8][row128][8] 16KB
    __shared__ __attribute__((aligned(16))) unsigned short B_l[8 * BPAD2 * 8];   // [kb8][col257][8]

    int tid = threadIdx.x;
    int lane = tid & 63;
    int wid = tid >> 6;
    int wr = wid >> 2, wc = wid & 3;   // 2 x 4 waves: 64 rows x 64 cols each
    int q = lane >> 4, rr = lane & 15;

    const unsigned short* asrc = hidp + (size_t)(ptile * 56) * 8192;

    // B staging: c = tid>>1 (row of w2), kh = tid&1 (32 consecutive k)
    int c = tid >> 1;
    int kh = tid & 1;
    const float* bs = w2 + ((size_t)e * HID_DIM + nt * 256 + c) * INTER + kh * 32;
    int bo0 = ((kh * 4 + 0) * BPAD2 + c) * 8;
    int bo1 = ((kh * 4 + 1) * BPAD2 + c) * 8;
    int bo2 = ((kh * 4 + 2) * BPAD2 + c) * 8;
    int bo3 = ((kh * 4 + 3) * BPAD2 + c) * 8;

    f32x4 acc[4][4];
#pragma unroll
    for (int i = 0; i < 4; ++i)
#pragma unroll
        for (int j = 0; j < 4; ++j) acc[i][j] = 0.f;

    float4 s0, s1, s2, s3, s4, s5, s6, s7;
#define G2_LOADB(KT) do {                                                     \
        const float* p_ = bs + (size_t)(KT) * 64;                             \
        s0 = *reinterpret_cast<const float4*>(p_);                            \
        s1 = *reinterpret_cast<const float4*>(p_ + 4);                        \
        s2 = *reinterpret_cast<const float4*>(p_ + 8);                        \
        s3 = *reinterpret_cast<const float4*>(p_ + 12);                       \
        s4 = *reinterpret_cast<const float4*>(p_ + 16);                       \
        s5 = *reinterpret_cast<const float4*>(p_ + 20);                       \
        s6 = *reinterpret_cast<const float4*>(p_ + 24);                       \
        s7 = *reinterpret_cast<const float4*>(p_ + 28);                       \
    } while (0)

    int kt0 = ks * 14;
    G2_LOADB(kt0);
    for (int t = 0; t < 14; ++t) {
        int kt = kt0 + t;
        const unsigned short* as_ = asrc + (size_t)kt * 8192;
        gload_lds16(as_ + tid * 8, A_l + tid * 8);
        gload_lds16(as_ + (512 + tid) * 8, A_l + (512 + tid) * 8);
        *reinterpret_cast<ushort8*>(B_l + bo0) = cvt8(s0, s1);
        *reinterpret_cast<ushort8*>(B_l + bo1) = cvt8(s2, s3);
        *reinterpret_cast<ushort8*>(B_l + bo2) = cvt8(s4, s5);
        *reinterpret_cast<ushort8*>(B_l + bo3) = cvt8(s6, s7);
        __syncthreads();
        if (t < 13) G2_LOADB(kt + 1);          // prefetch overlaps MFMA phase
#pragma unroll
        for (int kk = 0; kk < 2; ++kk) {
            short8 a[4], b[4];
            const unsigned short* abase = A_l + ((kk * 4 + q) * 128 + wr * 64 + rr) * 8;
            const unsigned short* bbase = B_l + ((kk * 4 + q) * BPAD2 + wc * 64 + rr) * 8;
#pragma unroll
            for (int i = 0; i < 4; ++i) a[i] = *reinterpret_cast<const short8*>(abase + i * 128);
#pragma unroll
            for (int j = 0; j < 4; ++j) b[j] = *reinterpret_cast<const short8*>(bbase + j * 128);
#pragma unroll
            for (int i = 0; i < 4; ++i)
#pragma unroll
                for (int j = 0; j < 4; ++j) acc[i][j] = mfma16(a[i], b[j], acc[i][j]);
        }
        __syncthreads();
    }
#undef G2_LOADB

    int rb = wr * 64 + q * 4;
    int hb = nt * 256 + wc * 64 + rr;
#pragma unroll
    for (int i = 0; i < 4; ++i) {
#pragma unroll
        for (int r = 0; r < 4; ++r) {
            int lrow = rb + i * 16 + r;
            int grow = tm * 128 + lrow;
            if (grow < cnt) {
                int p = off + grow;
                int tok = perm_token[p];
                float gate = perm_gate[p];
#pragma unroll
                for (int j = 0; j < 4; ++j)
                    atomicAdd(&out[(size_t)tok * HID_DIM + hb + j * 16], acc[i][j][r] * gate);
            }
        }
    }
}

extern "C" void kernel_launch(void* const* d_in, const int* in_sizes, int n_in,
                              void* d_out, int out_size, void* d_ws, size_t ws_size,
                              hipStream_t stream) {
    const float* x  = (const float*)d_in[0];
    const float* gw = (const float*)d_in[1];
    const float* w1 = (const float*)d_in[2];
    const float* w2 = (const float*)d_in[3];
    const float* w3 = (const float*)d_in[4];
    float* out = (float*)d_out;

    char* ws = (char*)d_ws;
    int*   ctl        = (int*)ws;                              // 4KB
    int*   topk_e     = (int*)(ws + 4096);                     // 16KB
    float* topk_w     = (float*)(ws + 20480);                  // 16KB
    int*   perm_token = (int*)(ws + 36864);                    // 20KB (5120)
    float* perm_gate  = (float*)(ws + 57344);                  // 20KB
    unsigned short* xgp  = (unsigned short*)(ws + (1ull << 20));        // 10.49MB @1MB
    unsigned short* hidp = (unsigned short*)(ws + 12582912);            // 36.7MB @12MB

    hipMemsetAsync(ctl, 0, 512, stream);
    hipMemsetAsync(perm_token, 0, PTILES * 128 * sizeof(int), stream);
    hipMemsetAsync(out, 0, (size_t)out_size * sizeof(float), stream);

    router_k<<<dim3(T_TOKENS / 4), 256, 0, stream>>>(x, gw, topk_e, topk_w, ctl);
    prefix_k<<<dim3(1), 64, 0, stream>>>(ctl);
    scatter_k<<<dim3(T_TOKENS / 256), 256, 0, stream>>>(topk_e, topk_w, ctl, perm_token, perm_gate);
    pack_x_k<<<dim3(PTILES, 16), 256, 0, stream>>>(x, perm_token, xgp);
    gemm1_k<<<dim3(224, 5), 512, 0, stream>>>(xgp, w1, w3, ctl, hidp);
    gemm2_k<<<dim3(32, 5, 4), 512, 0, stream>>>(hidp, w2, ctl, perm_token, perm_gate, out);
}

// Round 10
// 459.589 us; speedup vs baseline: 1.2985x; 1.0974x over previous
//
#include <hip/hip_runtime.h>
#include <hip/hip_bf16.h>
#include <stdint.h>

#define T_TOKENS 2048
#define HID_DIM 1024
#define INTER 3584
#define NEXP 8
#define PTILES 40

typedef float f32x4 __attribute__((ext_vector_type(4)));
typedef short short8 __attribute__((ext_vector_type(8)));
typedef unsigned short ushort8 __attribute__((ext_vector_type(8)));

__device__ __forceinline__ f32x4 mfma16(short8 a, short8 b, f32x4 c) {
    return __builtin_amdgcn_mfma_f32_16x16x32_bf16(a, b, c, 0, 0, 0);
}

__device__ __forceinline__ unsigned short f2bf(float f) {
    union { __hip_bfloat16 h; unsigned short u; } cv;
    cv.h = __float2bfloat16(f);
    return cv.u;
}

__device__ __forceinline__ ushort8 cvt8(float4 v0, float4 v1) {
    ushort8 u;
    u[0] = f2bf(v0.x); u[1] = f2bf(v0.y); u[2] = f2bf(v0.z); u[3] = f2bf(v0.w);
    u[4] = f2bf(v1.x); u[5] = f2bf(v1.y); u[6] = f2bf(v1.z); u[7] = f2bf(v1.w);
    return u;
}

__device__ __forceinline__ ushort4 cvt4(float4 v) {
    ushort4 u;
    u.x = f2bf(v.x); u.y = f2bf(v.y); u.z = f2bf(v.z); u.w = f2bf(v.w);
    return u;
}

// ---------------- router: fp32 logits, top-2, renorm weights, per-expert counts ----------------
__global__ void router_k(const float* __restrict__ x, const float* __restrict__ gw,
                         int* __restrict__ topk_e, float* __restrict__ topk_w,
                         int* __restrict__ ctl) {
    int lane = threadIdx.x & 63;
    int wid = threadIdx.x >> 6;
    int t = blockIdx.x * 4 + wid;
    const float* xr = x + (size_t)t * HID_DIM;

    float acc[NEXP];
#pragma unroll
    for (int e = 0; e < NEXP; ++e) acc[e] = 0.f;

#pragma unroll
    for (int j = 0; j < 4; ++j) {
        int c = j * 256 + lane * 4;
        float4 v = *reinterpret_cast<const float4*>(xr + c);
#pragma unroll
        for (int e = 0; e < NEXP; ++e) {
            float4 g = *reinterpret_cast<const float4*>(gw + e * HID_DIM + c);
            acc[e] += v.x * g.x + v.y * g.y + v.z * g.z + v.w * g.w;
        }
    }
#pragma unroll
    for (int off = 32; off > 0; off >>= 1)
#pragma unroll
        for (int e = 0; e < NEXP; ++e) acc[e] += __shfl_xor(acc[e], off, 64);

    if (lane == 0) {
        int e0 = 0;
#pragma unroll
        for (int e = 1; e < NEXP; ++e) if (acc[e] > acc[e0]) e0 = e;
        int e1 = -1;
        float b1 = 0.f;
#pragma unroll
        for (int e = 0; e < NEXP; ++e) {
            if (e == e0) continue;
            if (e1 < 0 || acc[e] > b1) { e1 = e; b1 = acc[e]; }
        }
        float p1 = __expf(b1 - acc[e0]);
        float s = 1.f + p1;
        topk_e[2 * t] = e0; topk_e[2 * t + 1] = e1;
        topk_w[2 * t] = 1.f / s; topk_w[2 * t + 1] = p1 / s;
        atomicAdd(&ctl[e0], 1);
        atomicAdd(&ctl[e1], 1);
    }
}

// ctl: [0..8) counts, [16..24) cursors, [32..40) 128-aligned offsets
__global__ void prefix_k(int* __restrict__ ctl) {
    if (threadIdx.x == 0) {
        int r = 0;
        for (int e = 0; e < NEXP; ++e) {
            ctl[32 + e] = r;
            r += (ctl[e] + 127) & ~127;
            ctl[16 + e] = 0;
        }
    }
}

__global__ void scatter_k(const int* __restrict__ topk_e, const float* __restrict__ topk_w,
                          int* __restrict__ ctl, int* __restrict__ perm_token,
                          float* __restrict__ perm_gate) {
    int t = blockIdx.x * 256 + threadIdx.x;
    if (t >= T_TOKENS) return;
#pragma unroll
    for (int k = 0; k < 2; ++k) {
        int e = topk_e[2 * t + k];
        int p = ctl[32 + e] + atomicAdd(&ctl[16 + e], 1);
        perm_token[p] = t;
        perm_gate[p] = topk_w[2 * t + k];
    }
}

// ---- gather routed tokens into packed A layout [ptile][kt16][kb8][row128][8], fp32->bf16 ----
__global__ __launch_bounds__(256) void pack_x_k(const float* __restrict__ x,
                                                const int* __restrict__ perm_token,
                                                unsigned short* __restrict__ xgp) {
    int ptile = blockIdx.x;
    int kt = blockIdx.y;
    int row = threadIdx.x & 127;
    int kh = threadIdx.x >> 7;
    int tok = perm_token[ptile * 128 + row];
    const float* s = x + (size_t)tok * HID_DIM + kt * 64 + kh * 32;
    unsigned short* d = xgp + (size_t)ptile * 131072 + (size_t)kt * 8192;
#pragma unroll
    for (int kb2 = 0; kb2 < 4; ++kb2) {
        int kb = kh * 4 + kb2;
        float4 v0 = *reinterpret_cast<const float4*>(s + kb2 * 8);
        float4 v1 = *reinterpret_cast<const float4*>(s + kb2 * 8 + 4);
        *reinterpret_cast<ushort8*>(d + (kb * 128 + row) * 8) = cvt8(v0, v1);
    }
}

// ---------------- GEMM1 weight-once: hid = silu(Xg@w1^T)*(Xg@w3^T) ----------------
// Block = (e, 32-col strip of w1 AND w3). Loops over ALL row-tiles of the expert
// (chunks of 4, acc in regs). Weights stream HBM once; A frags read directly from
// L2/L3-resident xgp (no A LDS, no global_load_lds). 512 thr / 8 waves, wave = 16
// rows/tile x all 64 cols. Grid 896: e = x&7 (XCD-aligned), nt = x>>3 (0..111).
__global__ __launch_bounds__(512) void gemm1_k(
    const unsigned short* __restrict__ xgp,
    const float* __restrict__ w1, const float* __restrict__ w3,
    const int* __restrict__ ctl, unsigned short* __restrict__ hidp) {
    int e = blockIdx.x & 7;
    int nt = blockIdx.x >> 3;         // 0..111: cols nt*32..+32 of both w1,w3
    int cnt = ctl[e];
    if (cnt == 0) return;
    int ntm = (cnt + 127) >> 7;
    int pt0 = ctl[32 + e] >> 7;

    __shared__ __attribute__((aligned(16))) unsigned short B_l[8 * 66 * 8]; // [kb8][col64+pad][8]

    int tid = threadIdx.x;
    int lane = tid & 63;
    int w = tid >> 6;                 // wave = row-frag group (16 rows per tile)
    int q = lane >> 4, rr = lane & 15;

    // B staging: thread t -> w-row brow (0..63: 0-31 w1cols, 32-63 w3cols), 8 consecutive k
    int brow = tid >> 3;
    int ko = (tid & 7) * 8;
    const float* wsrc = (brow & 32) ? w3 : w1;
    const float* bsrc = wsrc + ((size_t)e * INTER + nt * 32 + (brow & 31)) * HID_DIM + ko;
    int bo = ((tid & 7) * 66 + brow) * 8;

    for (int base = 0; base < ntm; base += 4) {
        const unsigned short* at[4];
#pragma unroll
        for (int tt = 0; tt < 4; ++tt) {
            int idx = base + tt;
            at[tt] = xgp + (size_t)(pt0 + (idx < ntm ? idx : 0)) * 131072;
        }
        f32x4 acc1[4][2], acc3[4][2];
#pragma unroll
        for (int tt = 0; tt < 4; ++tt)
#pragma unroll
            for (int j = 0; j < 2; ++j) { acc1[tt][j] = 0.f; acc3[tt][j] = 0.f; }

        float4 f0 = *reinterpret_cast<const float4*>(bsrc);
        float4 f1 = *reinterpret_cast<const float4*>(bsrc + 4);
        for (int kt = 0; kt < 16; ++kt) {
            *reinterpret_cast<ushort8*>(B_l + bo) = cvt8(f0, f1);
            __syncthreads();                                   // B visible
            if (kt < 15) {                                     // prefetch overlaps MFMA
                f0 = *reinterpret_cast<const float4*>(bsrc + (kt + 1) * 64);
                f1 = *reinterpret_cast<const float4*>(bsrc + (kt + 1) * 64 + 4);
            }
#pragma unroll
            for (int kk = 0; kk < 2; ++kk) {
                int ar = ((kk * 4 + q) * 128 + w * 16 + rr) * 8;
                short8 a[4];
#pragma unroll
                for (int tt = 0; tt < 4; ++tt)
                    a[tt] = *reinterpret_cast<const short8*>(at[tt] + (size_t)kt * 8192 + ar);
                const unsigned short* bb = B_l + ((kk * 4 + q) * 66 + rr) * 8;
                short8 b1v[2], b3v[2];
                b1v[0] = *reinterpret_cast<const short8*>(bb);
                b1v[1] = *reinterpret_cast<const short8*>(bb + 128);
                b3v[0] = *reinterpret_cast<const short8*>(bb + 256);
                b3v[1] = *reinterpret_cast<const short8*>(bb + 384);
#pragma unroll
                for (int tt = 0; tt < 4; ++tt)
#pragma unroll
                    for (int j = 0; j < 2; ++j) {
                        acc1[tt][j] = mfma16(a[tt], b1v[j], acc1[tt][j]);
                        acc3[tt][j] = mfma16(a[tt], b3v[j], acc3[tt][j]);
                    }
            }
            __syncthreads();                                   // readers done before overwrite
        }

        // epilogue: silu(g)*u -> packed hid [ptile][kt56][kb8][row128][8]
        int lrow = w * 16 + q * 4;
        int tile56 = nt >> 1;
        int colbase = (nt & 1) * 32;
#pragma unroll
        for (int tt = 0; tt < 4; ++tt) {
            if (base + tt < ntm) {
                size_t hb = (size_t)((pt0 + base + tt) * 56 + tile56) * 8192;
                int rowoff = (base + tt) * 128 + lrow;
#pragma unroll
                for (int j = 0; j < 2; ++j) {
                    int hcol = colbase + j * 16 + rr;      // 0..63 within hid tile
                    int kb = hcol >> 3, w8 = hcol & 7;
#pragma unroll
                    for (int ri = 0; ri < 4; ++ri) {
                        if (rowoff + ri < cnt) {
                            float g = acc1[tt][j][ri];
                            float u = acc3[tt][j][ri];
                            float h = (g / (1.f + __expf(-g))) * u;
                            hidp[hb + (kb * 128 + lrow + ri) * 8 + w8] = f2bf(h);
                        }
                    }
                }
            }
        }
    }
}

// ---------------- GEMM2 weight-once: out[tok] += gate*(hid @ w2^T) ----------------
// Block = (e, 32 out-cols, K-half). Loops all row-tiles (chunks of 4). w2 read once
// (K-split halves are disjoint). A frags direct from hidp (L2/L3). 512 thr / 8 waves.
// Grid 512: e = x&7, nt = (x>>3)&31, ks = x>>8.
__global__ __launch_bounds__(512) void gemm2_k(
    const unsigned short* __restrict__ hidp, const float* __restrict__ w2,
    const int* __restrict__ ctl, const int* __restrict__ perm_token,
    const float* __restrict__ perm_gate, float* __restrict__ out) {
    int e = blockIdx.x & 7;
    int nt = (blockIdx.x >> 3) & 31;  // 0..31: out cols nt*32..+32
    int ks = blockIdx.x >> 8;         // 0..1: kt in [ks*28, ks*28+28)
    int cnt = ctl[e];
    if (cnt == 0) return;
    int ntm = (cnt + 127) >> 7;
    int off = ctl[32 + e];
    int pt0 = off >> 7;

    __shared__ __attribute__((aligned(16))) unsigned short B_l[8 * 34 * 8]; // [kb8][col32+pad][8]

    int tid = threadIdx.x;
    int lane = tid & 63;
    int w = tid >> 6;
    int q = lane >> 4, rr = lane & 15;

    // B staging: thread t -> w2-row brow (0..31), 4 consecutive k
    int brow = tid >> 4;
    int ko = (tid & 15) * 4;
    const float* bsrc = w2 + ((size_t)e * HID_DIM + nt * 32 + brow) * INTER + (size_t)ks * 28 * 64 + ko;
    int bo = ((ko >> 3) * 34 + brow) * 8 + (ko & 7);

    int kt0 = ks * 28;
    for (int base = 0; base < ntm; base += 4) {
        const unsigned short* at[4];
#pragma unroll
        for (int tt = 0; tt < 4; ++tt) {
            int idx = base + tt;
            at[tt] = hidp + (size_t)(pt0 + (idx < ntm ? idx : 0)) * 56 * 8192;
        }
        f32x4 acc[4][2];
#pragma unroll
        for (int tt = 0; tt < 4; ++tt)
#pragma unroll
            for (int j = 0; j < 2; ++j) acc[tt][j] = 0.f;

        float4 f0 = *reinterpret_cast<const float4*>(bsrc);
        for (int t = 0; t < 28; ++t) {
            int kt = kt0 + t;
            *reinterpret_cast<ushort4*>(B_l + bo) = cvt4(f0);
            __syncthreads();
            if (t < 27) f0 = *reinterpret_cast<const float4*>(bsrc + (t + 1) * 64);
#pragma unroll
            for (int kk = 0; kk < 2; ++kk) {
                int ar = ((kk * 4 + q) * 128 + w * 16 + rr) * 8;
                short8 a[4];
#pragma unroll
                for (int tt = 0; tt < 4; ++tt)
                    a[tt] = *reinterpret_cast<const short8*>(at[tt] + (size_t)kt * 8192 + ar);
                const unsigned short* bb = B_l + ((kk * 4 + q) * 34 + rr) * 8;
                short8 b[2];
                b[0] = *reinterpret_cast<const short8*>(bb);
                b[1] = *reinterpret_cast<const short8*>(bb + 128);
#pragma unroll
                for (int tt = 0; tt < 4; ++tt)
#pragma unroll
                    for (int j = 0; j < 2; ++j)
                        acc[tt][j] = mfma16(a[tt], b[j], acc[tt][j]);
            }
            __syncthreads();
        }

        int lrow = w * 16 + q * 4;
#pragma unroll
        for (int tt = 0; tt < 4; ++tt) {
            if (base + tt < ntm) {
                int rowoff = (base + tt) * 128 + lrow;
#pragma unroll
                for (int ri = 0; ri < 4; ++ri) {
                    int grow = rowoff + ri;
                    if (grow < cnt) {
                        int p = off + grow;
                        int tok = perm_token[p];
                        float gate = perm_gate[p];
#pragma unroll
                        for (int j = 0; j < 2; ++j) {
                            int col = nt * 32 + j * 16 + rr;
                            atomicAdd(&out[(size_t)tok * HID_DIM + col], acc[tt][j][ri] * gate);
                        }
                    }
                }
            }
        }
    }
}

extern "C" void kernel_launch(void* const* d_in, const int* in_sizes, int n_in,
                              void* d_out, int out_size, void* d_ws, size_t ws_size,
                              hipStream_t stream) {
    const float* x  = (const float*)d_in[0];
    const float* gw = (const float*)d_in[1];
    const float* w1 = (const float*)d_in[2];
    const float* w2 = (const float*)d_in[3];
    const float* w3 = (const float*)d_in[4];
    float* out = (float*)d_out;

    char* ws = (char*)d_ws;
    int*   ctl        = (int*)ws;
    int*   topk_e     = (int*)(ws + 4096);
    float* topk_w     = (float*)(ws + 20480);
    int*   perm_token = (int*)(ws + 36864);
    float* perm_gate  = (float*)(ws + 57344);
    unsigned short* xgp  = (unsigned short*)(ws + (1ull << 20));   // 10.49MB @1MB
    unsigned short* hidp = (unsigned short*)(ws + 12582912);       // 36.7MB @12MB

    hipMemsetAsync(ctl, 0, 512, stream);
    hipMemsetAsync(perm_token, 0, PTILES * 128 * sizeof(int), stream);
    hipMemsetAsync(out, 0, (size_t)out_size * sizeof(float), stream);

    router_k<<<dim3(T_TOKENS / 4), 256, 0, stream>>>(x, gw, topk_e, topk_w, ctl);
    prefix_k<<<dim3(1), 64, 0, stream>>>(ctl);
    scatter_k<<<dim3(T_TOKENS / 256), 256, 0, stream>>>(topk_e, topk_w, ctl, perm_token, perm_gate);
    pack_x_k<<<dim3(PTILES, 16), 256, 0, stream>>>(x, perm_token, xgp);
    gemm1_k<<<dim3(896), 512, 0, stream>>>(xgp, w1, w3, ctl, hidp);
    gemm2_k<<<dim3(512), 512, 0, stream>>>(hidp, w2, ctl, perm_token, perm_gate, out);
}

// Round 11
// 341.025 us; speedup vs baseline: 1.7500x; 1.3477x over previous
//
#include <hip/hip_runtime.h>
#include <hip/hip_bf16.h>
#include <stdint.h>

#define T_TOKENS 2048
#define HID_DIM 1024
#define INTER 3584
#define NEXP 8
#define PTILES 40   // max padded row-tiles: 4096/128 + 8 alignment pads

typedef float f32x4 __attribute__((ext_vector_type(4)));
typedef short short8 __attribute__((ext_vector_type(8)));
typedef unsigned short ushort8 __attribute__((ext_vector_type(8)));

#define AS1 __attribute__((address_space(1)))
#define AS3 __attribute__((address_space(3)))

__device__ __forceinline__ void gload_lds16(const void* g, void* l) {
    __builtin_amdgcn_global_load_lds((AS1 void*)g, (AS3 void*)l, 16, 0, 0);
}

__device__ __forceinline__ f32x4 mfma16(short8 a, short8 b, f32x4 c) {
    return __builtin_amdgcn_mfma_f32_16x16x32_bf16(a, b, c, 0, 0, 0);
}

__device__ __forceinline__ unsigned short f2bf(float f) {
    union { __hip_bfloat16 h; unsigned short u; } cv;
    cv.h = __float2bfloat16(f);
    return cv.u;
}

__device__ __forceinline__ ushort8 cvt8(float4 v0, float4 v1) {
    ushort8 u;
    u[0] = f2bf(v0.x); u[1] = f2bf(v0.y); u[2] = f2bf(v0.z); u[3] = f2bf(v0.w);
    u[4] = f2bf(v1.x); u[5] = f2bf(v1.y); u[6] = f2bf(v1.z); u[7] = f2bf(v1.w);
    return u;
}

// ---- weight fp32 -> bf16 flat copy (row-major preserved; both sides coalesced) ----
// grid (7168, 1, 3): 16 floats per thread; lanes read 64B contiguous, write 32B.
__global__ __launch_bounds__(256) void cvt_k(const float* __restrict__ w1, const float* __restrict__ w2,
                                             const float* __restrict__ w3,
                                             unsigned short* __restrict__ w1b,
                                             unsigned short* __restrict__ w2b,
                                             unsigned short* __restrict__ w3b) {
    const float* src;
    unsigned short* dst;
    if (blockIdx.z == 0) { src = w1; dst = w1b; }
    else if (blockIdx.z == 1) { src = w3; dst = w3b; }
    else { src = w2; dst = w2b; }
    size_t i = ((size_t)blockIdx.x * 256 + threadIdx.x) * 16;
    float4 v0 = *reinterpret_cast<const float4*>(src + i);
    float4 v1 = *reinterpret_cast<const float4*>(src + i + 4);
    float4 v2 = *reinterpret_cast<const float4*>(src + i + 8);
    float4 v3 = *reinterpret_cast<const float4*>(src + i + 12);
    *reinterpret_cast<ushort8*>(dst + i) = cvt8(v0, v1);
    *reinterpret_cast<ushort8*>(dst + i + 8) = cvt8(v2, v3);
}

// ---------------- router: fp32 logits, top-2, renorm weights, per-expert counts ----------------
__global__ void router_k(const float* __restrict__ x, const float* __restrict__ gw,
                         int* __restrict__ topk_e, float* __restrict__ topk_w,
                         int* __restrict__ ctl) {
    int lane = threadIdx.x & 63;
    int wid = threadIdx.x >> 6;
    int t = blockIdx.x * 4 + wid;
    const float* xr = x + (size_t)t * HID_DIM;

    float acc[NEXP];
#pragma unroll
    for (int e = 0; e < NEXP; ++e) acc[e] = 0.f;

#pragma unroll
    for (int j = 0; j < 4; ++j) {
        int c = j * 256 + lane * 4;
        float4 v = *reinterpret_cast<const float4*>(xr + c);
#pragma unroll
        for (int e = 0; e < NEXP; ++e) {
            float4 g = *reinterpret_cast<const float4*>(gw + e * HID_DIM + c);
            acc[e] += v.x * g.x + v.y * g.y + v.z * g.z + v.w * g.w;
        }
    }
#pragma unroll
    for (int off = 32; off > 0; off >>= 1)
#pragma unroll
        for (int e = 0; e < NEXP; ++e) acc[e] += __shfl_xor(acc[e], off, 64);

    if (lane == 0) {
        int e0 = 0;
#pragma unroll
        for (int e = 1; e < NEXP; ++e) if (acc[e] > acc[e0]) e0 = e;
        int e1 = -1;
        float b1 = 0.f;
#pragma unroll
        for (int e = 0; e < NEXP; ++e) {
            if (e == e0) continue;
            if (e1 < 0 || acc[e] > b1) { e1 = e; b1 = acc[e]; }
        }
        float p1 = __expf(b1 - acc[e0]);
        float s = 1.f + p1;
        topk_e[2 * t] = e0; topk_e[2 * t + 1] = e1;
        topk_w[2 * t] = 1.f / s; topk_w[2 * t + 1] = p1 / s;
        atomicAdd(&ctl[e0], 1);
        atomicAdd(&ctl[e1], 1);
    }
}

// ctl: [0..8) counts, [16..24) cursors, [32..40) 128-aligned offsets,
//      [48] = n_slots, [64..64+40) slot table (e<<16|tm)
__global__ void prefix_k(int* __restrict__ ctl) {
    if (threadIdx.x == 0) {
        int r = 0, ns = 0;
        for (int e = 0; e < NEXP; ++e) {
            ctl[32 + e] = r;
            int c = ctl[e];
            r += (c + 127) & ~127;
            ctl[16 + e] = 0;
            int ntm = (c + 127) >> 7;
            for (int tm = 0; tm < ntm; ++tm) ctl[64 + ns++] = (e << 16) | tm;
        }
        ctl[48] = ns;
    }
}

__global__ void scatter_k(const int* __restrict__ topk_e, const float* __restrict__ topk_w,
                          int* __restrict__ ctl, int* __restrict__ perm_token,
                          float* __restrict__ perm_gate) {
    int t = blockIdx.x * 256 + threadIdx.x;
    if (t >= T_TOKENS) return;
#pragma unroll
    for (int k = 0; k < 2; ++k) {
        int e = topk_e[2 * t + k];
        int p = ctl[32 + e] + atomicAdd(&ctl[16 + e], 1);
        perm_token[p] = t;
        perm_gate[p] = topk_w[2 * t + k];
    }
}

// ---- gather routed tokens into packed A layout [ptile][kt16][kb8][row128][8], fp32->bf16 ----
__global__ __launch_bounds__(256) void pack_x_k(const float* __restrict__ x,
                                                const int* __restrict__ perm_token,
                                                unsigned short* __restrict__ xgp) {
    int ptile = blockIdx.x;
    int kt = blockIdx.y;
    int row = threadIdx.x & 127;
    int kh = threadIdx.x >> 7;  // 0..1: 32 k each (4 kb)
    int tok = perm_token[ptile * 128 + row];
    const float* s = x + (size_t)tok * HID_DIM + kt * 64 + kh * 32;
    unsigned short* d = xgp + (size_t)ptile * 131072 + (size_t)kt * 8192;
#pragma unroll
    for (int kb2 = 0; kb2 < 4; ++kb2) {
        int kb = kh * 4 + kb2;
        float4 v0 = *reinterpret_cast<const float4*>(s + kb2 * 8);
        float4 v1 = *reinterpret_cast<const float4*>(s + kb2 * 8 + 4);
        *reinterpret_cast<ushort8*>(d + (kb * 128 + row) * 8) = cvt8(v0, v1);
    }
}

// ---------------- GEMM1: hid = silu(Xg@w1^T)*(Xg@w3^T) ----------------
// 512 thr / 8 waves (2x4). BM=128, BN=128 per matrix, BK=64. LDS 48KB, 3 blocks/CU.
// A via global_load_lds from packed xgp (linear). B via global_load_lds from ROW-MAJOR
// bf16 with T21 src-swizzle: LDS [col128][64k] linear dst, src chunk = c' ^ (col&7);
// frag read applies matching XOR -> 2-way banks (free). 8 x 128B full lines per instr.
// Grid (224, 5): nt = x>>3, slot = (x&7)*5 + y.
__global__ __launch_bounds__(512, 4) void gemm1_k(
    const unsigned short* __restrict__ xgp,
    const unsigned short* __restrict__ w1b, const unsigned short* __restrict__ w3b,
    const int* __restrict__ ctl, unsigned short* __restrict__ hidp) {
    int ns = ctl[48];
    int nt = blockIdx.x >> 3;                       // 0..27 (128-col tiles)
    int slot = (blockIdx.x & 7) * 5 + blockIdx.y;   // 0..39
    if (slot >= ns) return;
    int et = ctl[64 + slot];
    int e = et >> 16, tm = et & 0xffff;
    int cnt = ctl[e];
    int off = ctl[32 + e];
    int ptile = (off >> 7) + tm;

    __shared__ __attribute__((aligned(16))) unsigned short A_l[8192];   // [kb8][row128][8] 16KB
    __shared__ __attribute__((aligned(16))) unsigned short B1_l[8192];  // [col128][k64] 16KB
    __shared__ __attribute__((aligned(16))) unsigned short B3_l[8192];

    int tid = threadIdx.x;
    int lane = tid & 63;
    int wid = tid >> 6;
    int wr = wid >> 2, wc = wid & 3;   // 2 x 4 waves: 64 rows x 32 cols each
    int q = lane >> 4, rr = lane & 15;

    const unsigned short* asrc = xgp + (size_t)ptile * 131072;

    // B staging: d = i*512+tid -> col = d>>3 (0..127), c' = d&7; src chunk = c' ^ (col&7)
    int col0 = tid >> 3;            // 0..63 (instr 0); instr 1 adds 64 (same &7)
    int c0 = tid & 7;
    int swzc = c0 ^ (col0 & 7);
    size_t rowbase = (size_t)(e * INTER + nt * 128) * HID_DIM;
    const unsigned short* b1r = w1b + rowbase + (size_t)col0 * HID_DIM + swzc * 8;
    const unsigned short* b3r = w3b + rowbase + (size_t)col0 * HID_DIM + swzc * 8;

    f32x4 acc1[4][2], acc3[4][2];
#pragma unroll
    for (int i = 0; i < 4; ++i)
#pragma unroll
        for (int j = 0; j < 2; ++j) { acc1[i][j] = 0.f; acc3[i][j] = 0.f; }

    for (int kt = 0; kt < 16; ++kt) {
        const unsigned short* as_ = asrc + (size_t)kt * 8192;
        gload_lds16(as_ + tid * 8, A_l + tid * 8);
        gload_lds16(as_ + (512 + tid) * 8, A_l + (512 + tid) * 8);
        gload_lds16(b1r + kt * 64, B1_l + tid * 8);
        gload_lds16(b1r + (size_t)64 * HID_DIM + kt * 64, B1_l + (512 + tid) * 8);
        gload_lds16(b3r + kt * 64, B3_l + tid * 8);
        gload_lds16(b3r + (size_t)64 * HID_DIM + kt * 64, B3_l + (512 + tid) * 8);
        __syncthreads();
#pragma unroll
        for (int kk = 0; kk < 2; ++kk) {
            short8 a[4], b1v[2], b3v[2];
            const unsigned short* abase = A_l + ((kk * 4 + q) * 128 + wr * 64 + rr) * 8;
#pragma unroll
            for (int i = 0; i < 4; ++i) a[i] = *reinterpret_cast<const short8*>(abase + i * 128);
            int swz = ((kk * 4 + q) ^ (rr & 7)) * 8;
            const unsigned short* b1base = B1_l + (wc * 32 + rr) * 64 + swz;
            const unsigned short* b3base = B3_l + (wc * 32 + rr) * 64 + swz;
#pragma unroll
            for (int j = 0; j < 2; ++j) {
                b1v[j] = *reinterpret_cast<const short8*>(b1base + j * 1024);
                b3v[j] = *reinterpret_cast<const short8*>(b3base + j * 1024);
            }
#pragma unroll
            for (int i = 0; i < 4; ++i)
#pragma unroll
                for (int j = 0; j < 2; ++j) {
                    acc1[i][j] = mfma16(a[i], b1v[j], acc1[i][j]);
                    acc3[i][j] = mfma16(a[i], b3v[j], acc3[i][j]);
                }
        }
        __syncthreads();
    }

    // epilogue: silu(g)*u -> packed hid [ptile][tile64][kb][row][8]
    int rbase = wr * 64 + q * 4;
#pragma unroll
    for (int i = 0; i < 4; ++i) {
#pragma unroll
        for (int r = 0; r < 4; ++r) {
            int lrow = rbase + i * 16 + r;
            if (tm * 128 + lrow < cnt) {
#pragma unroll
                for (int j = 0; j < 2; ++j) {
                    int cw = wc * 32 + j * 16 + rr;     // 0..127 within this 128-col tile
                    int tile = nt * 2 + (cw >> 6);
                    int cl = cw & 63;
                    float g = acc1[i][j][r];
                    float u = acc3[i][j][r];
                    float h = (g / (1.f + __expf(-g))) * u;
                    hidp[(size_t)(ptile * 56 + tile) * 8192 + ((cl >> 3) * 128 + lrow) * 8 + (cl & 7)] = f2bf(h);
                }
            }
        }
    }
}

// ---------------- GEMM2: out[tok] += gate*(hid @ w2^T). BM=128 BN=128, 2-way K-split ----------------
// 256 thr / 4 waves (2x2). B from row-major bf16 w2 with the same T21 src-swizzle;
// LDS B = 2 halves [col64][k64]. Grid (64, 5, 2): nty = x>>3, slot = (x&7)*5 + y, ks = z.
__global__ __launch_bounds__(256) void gemm2_k(
    const unsigned short* __restrict__ hidp, const unsigned short* __restrict__ w2b,
    const int* __restrict__ ctl, const int* __restrict__ perm_token,
    const float* __restrict__ perm_gate, float* __restrict__ out) {
    int ns = ctl[48];
    int nty = blockIdx.x >> 3;                      // 0..7
    int slot = (blockIdx.x & 7) * 5 + blockIdx.y;   // 0..39
    if (slot >= ns) return;
    int et = ctl[64 + slot];
    int e = et >> 16, tm = et & 0xffff;
    int ks = blockIdx.z;              // K-split half: kt in [ks*28, ks*28+28)
    int cnt = ctl[e];
    int off = ctl[32 + e];
    int ptile = (off >> 7) + tm;

    __shared__ __attribute__((aligned(16))) unsigned short A_l[8192]; // [kb8][row128][8] 16KB
    __shared__ __attribute__((aligned(16))) unsigned short B_l[8192]; // 2 halves [col64][k64] 16KB

    int tid = threadIdx.x;
    int lane = tid & 63;
    int wid = tid >> 6;
    int wr = wid >> 1, wc = wid & 1;
    int q = lane >> 4, rr = lane & 15;

    const unsigned short* asrc = hidp + (size_t)(ptile * 56) * 8192;

    // B staging: d = i*256+tid (i 0..3) -> col_g = d>>3 (0..127), c' = d&7
    int colg0 = tid >> 3;           // 0..31; instr i adds i*32 (same &7)
    int c0 = tid & 7;
    int swzc = c0 ^ (colg0 & 7);
    const unsigned short* b2r = w2b + (size_t)(e * HID_DIM + nty * 128 + colg0) * INTER + swzc * 8;

    f32x4 acc[4][4];
#pragma unroll
    for (int i = 0; i < 4; ++i)
#pragma unroll
        for (int j = 0; j < 4; ++j) acc[i][j] = 0.f;

    int kt0 = ks * 28;
    for (int t = 0; t < 28; ++t) {
        int kt = kt0 + t;
        const unsigned short* as_ = asrc + (size_t)kt * 8192;
#pragma unroll
        for (int c = 0; c < 4; ++c)
            gload_lds16(as_ + (c * 256 + tid) * 8, A_l + (c * 256 + tid) * 8);
#pragma unroll
        for (int i = 0; i < 4; ++i)
            gload_lds16(b2r + (size_t)i * 32 * INTER + kt * 64, B_l + (i * 256 + tid) * 8);
        __syncthreads();
#pragma unroll
        for (int kk = 0; kk < 2; ++kk) {
            short8 a[4], b[4];
            const unsigned short* abase = A_l + ((kk * 4 + q) * 128 + wr * 64 + rr) * 8;
            int swz = ((kk * 4 + q) ^ (rr & 7)) * 8;
            const unsigned short* bbase = B_l + wc * 4096 + rr * 64 + swz;
#pragma unroll
            for (int i = 0; i < 4; ++i) a[i] = *reinterpret_cast<const short8*>(abase + i * 128);
#pragma unroll
            for (int j = 0; j < 4; ++j) b[j] = *reinterpret_cast<const short8*>(bbase + j * 1024);
#pragma unroll
            for (int i = 0; i < 4; ++i)
#pragma unroll
                for (int j = 0; j < 4; ++j) acc[i][j] = mfma16(a[i], b[j], acc[i][j]);
        }
        __syncthreads();
    }

    int rb = wr * 64 + q * 4;
    int hb = nty * 128 + wc * 64 + rr;
#pragma unroll
    for (int i = 0; i < 4; ++i) {
#pragma unroll
        for (int r = 0; r < 4; ++r) {
            int lrow = rb + i * 16 + r;
            int grow = tm * 128 + lrow;
            if (grow < cnt) {
                int p = off + grow;
                int tok = perm_token[p];
                float gate = perm_gate[p];
#pragma unroll
                for (int j = 0; j < 4; ++j)
                    atomicAdd(&out[(size_t)tok * HID_DIM + hb + j * 16], acc[i][j][r] * gate);
            }
        }
    }
}

extern "C" void kernel_launch(void* const* d_in, const int* in_sizes, int n_in,
                              void* d_out, int out_size, void* d_ws, size_t ws_size,
                              hipStream_t stream) {
    const float* x  = (const float*)d_in[0];
    const float* gw = (const float*)d_in[1];
    const float* w1 = (const float*)d_in[2];
    const float* w2 = (const float*)d_in[3];
    const float* w3 = (const float*)d_in[4];
    float* out = (float*)d_out;

    char* ws = (char*)d_ws;
    int*   ctl        = (int*)ws;                              // 4KB
    int*   topk_e     = (int*)(ws + 4096);
    float* topk_w     = (float*)(ws + 20480);
    int*   perm_token = (int*)(ws + 36864);
    float* perm_gate  = (float*)(ws + 57344);
    unsigned short* xgp  = (unsigned short*)(ws + (1ull << 20));        // 10.49MB @1MB
    unsigned short* hidp = (unsigned short*)(ws + 12582912);            // 36.7MB @12MB
    unsigned short* w1b  = (unsigned short*)(ws + 52428800);            // 58.7MB @50MB (row-major)
    unsigned short* w3b  = (unsigned short*)(ws + 111149056);           // 58.7MB
    unsigned short* w2b  = (unsigned short*)(ws + 169869312);           // 58.7MB (end ~218MB)

    hipMemsetAsync(ctl, 0, 512, stream);
    hipMemsetAsync(perm_token, 0, PTILES * 128 * sizeof(int), stream);
    hipMemsetAsync(out, 0, (size_t)out_size * sizeof(float), stream);

    cvt_k<<<dim3(7168, 1, 3), 256, 0, stream>>>(w1, w2, w3, w1b, w2b, w3b);
    router_k<<<dim3(T_TOKENS / 4), 256, 0, stream>>>(x, gw, topk_e, topk_w, ctl);
    prefix_k<<<dim3(1), 64, 0, stream>>>(ctl);
    scatter_k<<<dim3(T_TOKENS / 256), 256, 0, stream>>>(topk_e, topk_w, ctl, perm_token, perm_gate);
    pack_x_k<<<dim3(PTILES, 16), 256, 0, stream>>>(x, perm_token, xgp);
    gemm1_k<<<dim3(224, 5), 512, 0, stream>>>(xgp, w1b, w3b, ctl, hidp);
    gemm2_k<<<dim3(64, 5, 2), 256, 0, stream>>>(hidp, w2b, ctl, perm_token, perm_gate, out);
}